// Round 7
// baseline (937.493 us; speedup 1.0000x reference)
//
#include <hip/hip_runtime.h>

typedef unsigned short u16;
typedef unsigned int u32;
typedef __bf16 bf16x8 __attribute__((ext_vector_type(8)));
typedef float f32x4 __attribute__((ext_vector_type(4)));

#define B_ 2
#define T_ 2048
#define C_ 2048
#define H_ 16
#define HS_ 128
#define AL_ 10
#define C3_ 6144
#define MASKV (-3.0e38f)   // finite "-inf": exp(MASKV - m) == 0
#define MFMA16(a, b, c) __builtin_amdgcn_mfma_f32_16x16x32_bf16(a, b, c, 0, 0, 0)

__device__ __forceinline__ float b2f(u16 v) {
  union { u32 u; float f; } x; x.u = ((u32)v) << 16; return x.f;
}
__device__ __forceinline__ u16 f2b(float f) {
  u32 u = __builtin_bit_cast(u32, f);
  return (u16)((u + 0x7FFFu + ((u >> 16) & 1u)) >> 16);  // RNE
}
// fp32 -> bf16 -> fp32 (match the np ref's bf16-cast of fp32 inputs)
__device__ __forceinline__ float rb(float f) { return b2f(f2b(f)); }

// ---------------------------------------------------------------------------
// GEMM: C(MxN) = A(MxK) * B(NxK)^T, fp32 accum. 128x128 tile, BK=32,
// 4 waves x 64x64 quadrant. AF32/BF32: operand is fp32 in global (bf16-
// converted at staging) vs already-bf16. OUTF32: store fp32 (the harness
// output buffer is the reference's dtype = float32) vs bf16 (internal qkv).
// lda = A row stride in A's own elements.
// ---------------------------------------------------------------------------
template <bool AF32, bool BF32, bool OUTF32>
__global__ __launch_bounds__(256) void gemm_nt(
    const void* __restrict__ Ap, const void* __restrict__ Bp,
    void* __restrict__ Cp, int N, int K, int lda)
{
  __shared__ u16 lA[128 * 32];
  __shared__ u16 lB[128 * 32];
  const int tid  = threadIdx.x;
  const int lane = tid & 63, wave = tid >> 6;
  const int quad = lane >> 4, l16 = lane & 15;
  const int bm = blockIdx.y * 128, bn = blockIdx.x * 128;
  const int wm = (wave >> 1) * 64, wn = (wave & 1) * 64;
  const int srow = tid >> 1, scol = (tid & 1) * 16;   // 2 thr/row, 16 elem each
  f32x4 acc[4][4] = {};

  for (int k0 = 0; k0 < K; k0 += 32) {
    __align__(16) u16 abuf[16], bbuf[16];
    if constexpr (AF32) {
      const float* gA = (const float*)Ap + (size_t)(bm + srow) * lda + scol + k0;
      union { float4 v[4]; float s[16]; } fa;
#pragma unroll
      for (int j = 0; j < 4; j++) fa.v[j] = *(const float4*)(gA + j * 4);
#pragma unroll
      for (int j = 0; j < 16; j++) abuf[j] = f2b(fa.s[j]);
    } else {
      const u16* gA = (const u16*)Ap + (size_t)(bm + srow) * lda + scol + k0;
      *(uint4*)&abuf[0] = *(const uint4*)(gA);
      *(uint4*)&abuf[8] = *(const uint4*)(gA + 8);
    }
    if constexpr (BF32) {
      const float* gB = (const float*)Bp + (size_t)(bn + srow) * K + scol + k0;
      union { float4 v[4]; float s[16]; } fb;
#pragma unroll
      for (int j = 0; j < 4; j++) fb.v[j] = *(const float4*)(gB + j * 4);
#pragma unroll
      for (int j = 0; j < 16; j++) bbuf[j] = f2b(fb.s[j]);
    } else {
      const u16* gB = (const u16*)Bp + (size_t)(bn + srow) * K + scol + k0;
      *(uint4*)&bbuf[0] = *(const uint4*)(gB);
      *(uint4*)&bbuf[8] = *(const uint4*)(gB + 8);
    }
    __syncthreads();                       // prior-iter LDS reads done
    *(uint4*)&lA[srow * 32 + scol]     = *(uint4*)&abuf[0];
    *(uint4*)&lA[srow * 32 + scol + 8] = *(uint4*)&abuf[8];
    *(uint4*)&lB[srow * 32 + scol]     = *(uint4*)&bbuf[0];
    *(uint4*)&lB[srow * 32 + scol + 8] = *(uint4*)&bbuf[8];
    __syncthreads();
    bf16x8 af[4], bfv[4];
#pragma unroll
    for (int i = 0; i < 4; i++)
      af[i] = *(const bf16x8*)&lA[(wm + i * 16 + l16) * 32 + quad * 8];
#pragma unroll
    for (int i = 0; i < 4; i++)
      bfv[i] = *(const bf16x8*)&lB[(wn + i * 16 + l16) * 32 + quad * 8];
#pragma unroll
    for (int i = 0; i < 4; i++)
#pragma unroll
      for (int j = 0; j < 4; j++)
        acc[i][j] = MFMA16(af[i], bfv[j], acc[i][j]);
  }
  // C/D layout: col = lane&15, row = quad*4 + reg  [m89/m91 verified]
#pragma unroll
  for (int i = 0; i < 4; i++) {
#pragma unroll
    for (int r = 0; r < 4; r++) {
      const int row = bm + wm + i * 16 + quad * 4 + r;
      if constexpr (OUTF32) {
        float* crow = (float*)Cp + (size_t)row * N + bn + wn + l16;
#pragma unroll
        for (int j = 0; j < 4; j++)
          crow[j * 16] = acc[i][j][r];
      } else {
        u16* crow = (u16*)Cp + (size_t)row * N + bn + wn + l16;
#pragma unroll
        for (int j = 0; j < 4; j++)
          crow[j * 16] = f2b(acc[i][j][r]);
      }
    }
  }
}

// ---------------------------------------------------------------------------
// Adapter pqkv: ak/av[h][l][d] = bf16(adapter_emb[l]) . bf16(W_attn[...]),
// fp32 accum/out (160 KiB scratch in d_out, dead before proj overwrites).
// ---------------------------------------------------------------------------
__global__ __launch_bounds__(256) void adapter_pqkv(
    const float* __restrict__ emb, const float* __restrict__ W,
    float* __restrict__ akb, float* __restrict__ avb)
{
  const int tid = threadIdx.x;
  const int lane = tid & 63;
  const int w = blockIdx.x * 4 + (tid >> 6);      // 0..4095
  const int part = w >> 11;                        // 0 = k, 1 = v
  const int col = w & 2047;                        // h*128 + d
  const float* wrow = W + (size_t)(C_ + part * C_ + col) * C_;
  float acc[AL_];
#pragma unroll
  for (int l = 0; l < AL_; l++) acc[l] = 0.f;
  for (int i = 0; i < 32; i++) {
    const int c = i * 64 + lane;
    const float wv = rb(wrow[c]);
#pragma unroll
    for (int l = 0; l < AL_; l++) acc[l] += wv * rb(emb[l * C_ + c]);
  }
#pragma unroll
  for (int l = 0; l < AL_; l++) {
    for (int off = 32; off > 0; off >>= 1) acc[l] += __shfl_xor(acc[l], off);
  }
  if (lane == 0) {
    const int h = col >> 7, d = col & 127;
    float* dst = (part == 0 ? akb : avb) + (size_t)h * AL_ * HS_ + d;
#pragma unroll
    for (int l = 0; l < AL_; l++) dst[l * HS_] = acc[l];
  }
}

// ---------------------------------------------------------------------------
// RoPE in-place on qkv's q and k parts (qkv is bf16). rope table is FP32.
// One thread per (b,t,h,pair); each thread owns its aligned u32 pair.
// ---------------------------------------------------------------------------
__global__ __launch_bounds__(256) void rope_inplace(
    u16* __restrict__ qkv, const float* __restrict__ rope)
{
  const int g = blockIdx.x * 256 + threadIdx.x;
  const int j2 = g & 63;
  const int h  = (g >> 6) & 15;
  const int t  = (g >> 10) & 2047;
  const int b  = g >> 21;
  u16* src = qkv + (size_t)(b * T_ + t) * C3_ + h * HS_ + j2 * 2;
  const u32 qp = *(const u32*)(src);
  const u32 kp = *(const u32*)(src + C_);
  const float2 rp = *(const float2*)(rope + (t * 64 + j2) * 2);
  const float c = rb(rp.x), s = rb(rp.y);
  const float q0 = b2f((u16)qp), q1 = b2f((u16)(qp >> 16));
  const float k0 = b2f((u16)kp), k1 = b2f((u16)(kp >> 16));
  const float qr0 = q0 * c - q1 * s, qr1 = q1 * c + q0 * s;
  const float kr0 = k0 * c - k1 * s, kr1 = k1 * c + k0 * s;
  *(u32*)(src)      = (u32)f2b(qr0) | ((u32)f2b(qr1) << 16);
  *(u32*)(src + C_) = (u32)f2b(kr0) | ((u32)f2b(kr1) << 16);
}

// ---------------------------------------------------------------------------
// Flash attention + gated adapter attention. Q/K/V read from qkv (bf16,
// stride 3C); V transposed into LDS during staging. y written IN-PLACE over
// qkv's q-part (block-private patch). gating is FP32.
// ---------------------------------------------------------------------------
__global__ __launch_bounds__(256) void attn_flash(
    u16* __restrict__ qkv, const float* __restrict__ akbuf,
    const float* __restrict__ avbuf, const float* __restrict__ gating)
{
  __shared__ __align__(16) char smem[65536];
  u16* lQ  = (u16*)smem;               // [0,32768)  128 x 128
  u16* lK  = (u16*)(smem + 32768);     // [32768,40960)  32 keys x 128
  u16* lV  = (u16*)(smem + 40960);     // [40960,49152)  Vt: 128 d x 32 keys
  u16* lP  = (u16*)(smem + 49152);     // [49152,57344)  128 x 32
  u16* lAy = (u16*)(smem + 32768);     // overlay, used only after main loop

  const int tid  = threadIdx.x;
  const int lane = tid & 63, wave = tid >> 6;
  const int quad = lane >> 4, l16 = lane & 15;
  const int qt = blockIdx.x, h = blockIdx.y, b = blockIdx.z;
  u16* Qg = qkv + ((size_t)(b * T_) + qt * 128) * C3_ + h * HS_;          // q-part
  const u16* Kg = qkv + (size_t)(b * T_) * C3_ + C_ + h * HS_;            // k-part
  const u16* Vg = qkv + (size_t)(b * T_) * C3_ + 2 * C_ + h * HS_;        // v-part
  const float scale = 0.08838834764831845f;   // 1/sqrt(128)

#pragma unroll
  for (int i = 0; i < 8; i++) {                // Q tile (strided rows)
    const int e = (i * 256 + tid) * 8;
    const int row = e >> 7, col = e & 127;
    *(uint4*)&lQ[e] = *(const uint4*)(Qg + (size_t)row * C3_ + col);
  }
  f32x4 acc[2][8] = {};
  float mst[2][4], lst[2][4];
#pragma unroll
  for (int mt = 0; mt < 2; mt++)
#pragma unroll
    for (int r = 0; r < 4; r++) { mst[mt][r] = MASKV; lst[mt][r] = 0.f; }

  const int nkt = (qt + 1) * 4;
  const int krow = tid >> 3, kcol = (tid & 7) * 16;   // K & V staging coords
  for (int kt = 0; kt < nkt; kt++) {
    __syncthreads();                           // prior-iter lK/lV/lP reads done
    {
      const u16* ks = Kg + (size_t)(kt * 32 + krow) * C3_ + kcol;
      *(uint4*)&lK[krow * 128 + kcol]     = *(const uint4*)(ks);
      *(uint4*)&lK[krow * 128 + kcol + 8] = *(const uint4*)(ks + 8);
      // V: load rows [key][d], scatter transposed to lV[d][key]
      const u16* vs = Vg + (size_t)(kt * 32 + krow) * C3_ + kcol;
      union { uint4 v[2]; u16 e[16]; } vv;
      vv.v[0] = *(const uint4*)(vs);
      vv.v[1] = *(const uint4*)(vs + 8);
#pragma unroll
      for (int j = 0; j < 16; j++)
        lV[(kcol + j) * 32 + krow] = vv.e[j];
    }
    __syncthreads();
    // ---- S = Q K^T ----
    f32x4 sacc[2][2] = {};
#pragma unroll
    for (int kk = 0; kk < 4; kk++) {
      bf16x8 aq0 = *(const bf16x8*)&lQ[(wave * 32 + l16) * HS_ + kk * 32 + quad * 8];
      bf16x8 aq1 = *(const bf16x8*)&lQ[(wave * 32 + 16 + l16) * HS_ + kk * 32 + quad * 8];
      bf16x8 bk0 = *(const bf16x8*)&lK[l16 * HS_ + kk * 32 + quad * 8];
      bf16x8 bk1 = *(const bf16x8*)&lK[(16 + l16) * HS_ + kk * 32 + quad * 8];
      sacc[0][0] = MFMA16(aq0, bk0, sacc[0][0]);
      sacc[0][1] = MFMA16(aq0, bk1, sacc[0][1]);
      sacc[1][0] = MFMA16(aq1, bk0, sacc[1][0]);
      sacc[1][1] = MFMA16(aq1, bk1, sacc[1][1]);
    }
    // ---- online softmax ----
#pragma unroll
    for (int mt = 0; mt < 2; mt++) {
      float p0[4], p1[4], alpha[4];
#pragma unroll
      for (int r = 0; r < 4; r++) {
        const int qg = qt * 128 + wave * 32 + mt * 16 + quad * 4 + r;
        float s0 = sacc[mt][0][r] * scale;
        float s1 = sacc[mt][1][r] * scale;
        if (kt * 32 + l16 > qg)      s0 = MASKV;
        if (kt * 32 + 16 + l16 > qg) s1 = MASKV;
        float rmax = fmaxf(s0, s1);
#pragma unroll
        for (int off = 1; off < 16; off <<= 1)
          rmax = fmaxf(rmax, __shfl_xor(rmax, off));
        const float mnew = fmaxf(mst[mt][r], rmax);
        alpha[r] = __expf(mst[mt][r] - mnew);
        mst[mt][r] = mnew;
        p0[r] = __expf(s0 - mnew);
        p1[r] = __expf(s1 - mnew);
        float rs = p0[r] + p1[r];
#pragma unroll
        for (int off = 1; off < 16; off <<= 1)
          rs += __shfl_xor(rs, off);
        lst[mt][r] = lst[mt][r] * alpha[r] + rs;
      }
#pragma unroll
      for (int r = 0; r < 4; r++) {            // P: C-layout -> row-major LDS
        const int row = wave * 32 + mt * 16 + quad * 4 + r;
        lP[row * 32 + l16]      = f2b(p0[r]);
        lP[row * 32 + 16 + l16] = f2b(p1[r]);
      }
#pragma unroll
      for (int nt = 0; nt < 8; nt++)           // rescale O (lane-local alpha)
#pragma unroll
        for (int r = 0; r < 4; r++) acc[mt][nt][r] *= alpha[r];
    }
    // ---- fence: u16 P-stores ordered before bf16x8 P-loads ----
    __syncthreads();
    // ---- O += P V ----
#pragma unroll
    for (int mt = 0; mt < 2; mt++) {
      bf16x8 ap = *(const bf16x8*)&lP[(wave * 32 + mt * 16 + l16) * 32 + quad * 8];
#pragma unroll
      for (int nt = 0; nt < 8; nt++) {
        bf16x8 bv = *(const bf16x8*)&lV[(nt * 16 + l16) * 32 + quad * 8];
        acc[mt][nt] = MFMA16(ap, bv, acc[mt][nt]);
      }
    }
  }
  // ---- adapter attention (10 prefix keys, separate softmax) ----
  __syncthreads();                             // all PV reads done before lAy overlay
  if (tid < 128) {
    const int r = tid;
    const float* ak = akbuf + (size_t)h * AL_ * HS_;
    const float* av = avbuf + (size_t)h * AL_ * HS_;
    float sa[AL_];
    float smax = MASKV;
#pragma unroll
    for (int l = 0; l < AL_; l++) {
      float a = 0.f;
      for (int d = 0; d < HS_; d++) a += b2f(lQ[r * HS_ + d]) * ak[l * HS_ + d];
      sa[l] = a * scale;
      smax = fmaxf(smax, sa[l]);
    }
    float ssum = 0.f;
#pragma unroll
    for (int l = 0; l < AL_; l++) { sa[l] = __expf(sa[l] - smax); ssum += sa[l]; }
    const float inv = 1.f / ssum;
#pragma unroll
    for (int l = 0; l < AL_; l++) sa[l] *= inv;
    for (int d = 0; d < HS_; d++) {
      float a = 0.f;
#pragma unroll
      for (int l = 0; l < AL_; l++) a += sa[l] * av[l * HS_ + d];
      lAy[r * HS_ + d] = f2b(a);
    }
  }
  __syncthreads();
  // ---- epilogue: y = O/l + g*ay, written over qkv q-part (block's own patch)
  const float g = rb(gating[h]);
#pragma unroll
  for (int mt = 0; mt < 2; mt++) {
#pragma unroll
    for (int r = 0; r < 4; r++) {
      const int row = wave * 32 + mt * 16 + quad * 4 + r;
      const float linv = 1.f / lst[mt][r];
      u16* yrow = Qg + (size_t)row * C3_ + l16;
#pragma unroll
      for (int nt = 0; nt < 8; nt++) {
        const float v = acc[mt][nt][r] * linv + g * b2f(lAy[row * HS_ + nt * 16 + l16]);
        yrow[nt * 16] = f2b(v);
      }
    }
  }
}

// ---------------------------------------------------------------------------
extern "C" void kernel_launch(void* const* d_in, const int* in_sizes, int n_in,
                              void* d_out, int out_size, void* d_ws, size_t ws_size,
                              hipStream_t stream) {
  (void)out_size; (void)ws_size;
  // Inputs are FP32, dict order; bind by unique element count with dict-order
  // fallbacks. W_proj = LAST 4194304-elem input (mask idx 2 < W_proj idx 4).
  int ix = 0, irope = 1, iW = 3, iP = 4, iE = 5, iG = 6;
  for (int i = 0; i < n_in; i++) {
    switch (in_sizes[i]) {
      case 8388608:  ix = i;    break;   // x (2,2048,2048)
      case 262144:   irope = i; break;   // rope (2048,64,2)
      case 12582912: iW = i;    break;   // W_attn (6144,2048)
      case 20480:    iE = i;    break;   // adapter_emb (10,2048)
      case 16:       iG = i;    break;   // gating (1,16,1,1)
      case 4194304:  iP = i;    break;   // mask (idx 2) then W_proj (idx 4): last wins
      default: break;
    }
  }
  const float* x      = (const float*)d_in[ix];
  const float* rope   = (const float*)d_in[irope];
  const float* W_attn = (const float*)d_in[iW];
  const float* W_proj = (const float*)d_in[iP];
  const float* emb    = (const float*)d_in[iE];
  const float* gating = (const float*)d_in[iG];

  // Workspace: qkv bf16, 48 MiB. Adapter ak/av fp32 scratch lives at the
  // start of d_out (16 MiB fp32; scratch is dead before the proj GEMM
  // overwrites all of d_out). y is written in-place over qkv's q-part.
  u16*   qkv = (u16*)d_ws;
  float* akb = (float*)d_out;
  float* avb = akb + (size_t)H_ * AL_ * HS_;

  // qkv = bf16(x) @ bf16(W_attn)^T   (M=4096, N=6144, K=2048), bf16 out
  gemm_nt<true, true, false><<<dim3(48, 32), 256, 0, stream>>>(
      x, W_attn, qkv, 6144, 2048, 2048);
  adapter_pqkv<<<dim3(1024), 256, 0, stream>>>(emb, W_attn, akb, avb);
  rope_inplace<<<dim3(16384), 256, 0, stream>>>(qkv, rope);
  attn_flash<<<dim3(16, 16, 2), 256, 0, stream>>>(qkv, akb, avb, gating);
  // out = y @ bf16(W_proj)^T   (A = y bf16 strided in qkv, lda=6144), FP32 out
  gemm_nt<false, true, true><<<dim3(16, 32), 256, 0, stream>>>(
      qkv, W_proj, (float*)d_out, 2048, 2048, 6144);
}